// Round 9
// baseline (162.862 us; speedup 1.0000x reference)
//
#include <hip/hip_runtime.h>

#define NFULL 128
#define NOUT  122
#define NBLK  1248   // 4 batch x 4 wtile x 13 htile x 6 dchunk
#define PLANE 16384  // 128*128 floats

// DPP row_shl:k — lane i reads lane i+k within its 16-lane row (bound_ctrl -> 0)
template<int CTRL>
__device__ __forceinline__ float dppshl(float v) {
    return __int_as_float(
        __builtin_amdgcn_update_dpp(0, __float_as_int(v), CTRL, 0xF, 0xF, true));
}

__global__ __launch_bounds__(256, 3)
void ssim3d_kernel(const float* __restrict__ X, const float* __restrict__ Y,
                   const float* __restrict__ DR, double* __restrict__ wsout, int mode)
{
    __shared__ float sm[4];

    const int tid  = threadIdx.x;
    const int wave = tid >> 6;
    const int lane = tid & 63;
    const int h = lane & 15;       // row-in-tile 0..15 (low bits => DPP row)
    const int c = lane >> 4;       // colpair 0..3

    int bi = blockIdx.x;
    const int bb = bi & 3;  bi >>= 2;   // batch
    const int wt = bi & 3;  bi >>= 2;   // 4 w-tiles of 32
    const int ht = bi % 13;             // 13 h-tiles of 10
    const int dc = bi / 13;             // 6 d-chunks

    const int hb = ht * 10;
    int grow = hb + h; if (grow > NFULL - 1) grow = NFULL - 1;
    const int wbase = wt * 32 + wave * 8;
    int colb = wbase + 2 * c; if (colb > NFULL - 8) colb = NFULL - 8;
    const int csize = (dc < 2) ? 21 : 20;
    const int d0 = (dc < 2) ? 21 * dc : 42 + 20 * (dc - 2);
    const int nsl = csize + 6;          // slices d0..d0+nsl-1 (max = 127)

    // SSIM constants scaled by 343^2 (ratio-invariant; validated R4-R8)
    const float dr  = DR[bb];
    const float c1s = (0.01f * dr) * (0.01f * dr) * 117649.0f;
    const float c2s = (0.03f * dr) * (0.03f * dr) * 117649.0f;
    const float tni = 1.0f / 343.0f;
    const float kkA = 2.0f * 117649.0f / 342.0f;
    const float kkB = 117649.0f / 342.0f;

    const int gh  = hb + h;
    const int gw0 = wbase + 2 * c;
    const bool vh   = (h < 10) && (gh < NOUT);
    const bool vld0 = vh && (gw0 < NOUT);
    const bool vld1 = vh && (gw0 + 1 < NOUT);

    const size_t planeStride = (size_t)PLANE;
    const float* Xrow = X + (size_t)bb * NFULL * planeStride
                          + (size_t)(d0) * planeStride
                          + (size_t)grow * NFULL + colb;
    const float* Yrow = Y + (size_t)bb * NFULL * planeStride
                          + (size_t)(d0) * planeStride
                          + (size_t)grow * NFULL + colb;

    // ring/run over 10 components: [2q+j], j = output column 0/1
    float ring[7][10];
    float run[10];
#pragma unroll
    for (int k = 0; k < 7; ++k)
#pragma unroll
        for (int q = 0; q < 10; ++q) ring[k][q] = 0.f;
#pragma unroll
    for (int q = 0; q < 10; ++q) run[q] = 0.f;
    float acc = 0.0f;

    // Ping-pong register buffers for prefetch (parity = u&1, static under unroll)
    float2 bx[2][4], by[2][4];
    {
        const float* px = Xrow;
        const float* py = Yrow;
#pragma unroll
        for (int k = 0; k < 4; ++k) {
            bx[0][k] = *(const float2*)(px + 2 * k);
            by[0][k] = *(const float2*)(py + 2 * k);
        }
    }

    // Main loop: NO LDS, NO barriers, 14-deep unroll so parity & ring slot are static.
    for (int base = 0; base < nsl; base += 14) {
#pragma unroll
        for (int u = 0; u < 14; ++u) {
            const int s = base + u;
            if (s < nsl) {
                const int cur = u & 1;
                const int nxt = cur ^ 1;
                const int slot = u % 7;            // == s % 7 (base % 14 == 0)

                // ---- prefetch slice s+1 (clamped) into the other parity buffer ----
                const int sp = (s + 1 < nsl) ? (s + 1) : s;
                {
                    const float* px = Xrow + (size_t)sp * planeStride;
                    const float* py = Yrow + (size_t)sp * planeStride;
#pragma unroll
                    for (int k = 0; k < 4; ++k) {
                        bx[nxt][k] = *(const float2*)(px + 2 * k);
                        by[nxt][k] = *(const float2*)(py + 2 * k);
                    }
                }

                // ---- compute from current buffer ----
                float xs[8], ys[8];
#pragma unroll
                for (int k = 0; k < 4; ++k) {
                    xs[2 * k] = bx[cur][k].x; xs[2 * k + 1] = bx[cur][k].y;
                    ys[2 * k] = by[cur][k].x; ys[2 * k + 1] = by[cur][k].y;
                }
                float f[10];
                {
                    float sx = 0.f, sy = 0.f, sxx = 0.f, syy = 0.f, sxy = 0.f;
#pragma unroll
                    for (int k = 0; k < 7; ++k) {
                        sx += xs[k]; sy += ys[k];
                        sxx = fmaf(xs[k], xs[k], sxx);
                        syy = fmaf(ys[k], ys[k], syy);
                        sxy = fmaf(xs[k], ys[k], sxy);
                    }
                    f[0] = sx;  f[1] = sx - xs[0] + xs[7];
                    f[2] = sy;  f[3] = sy - ys[0] + ys[7];
                    f[4] = sxx; f[5] = sxx - xs[0] * xs[0] + xs[7] * xs[7];
                    f[6] = syy; f[7] = syy - ys[0] * ys[0] + ys[7] * ys[7];
                    f[8] = sxy; f[9] = sxy - xs[0] * ys[0] + xs[7] * ys[7];
                }

                // ---- H-sums: 7-tap across lanes h..h+6 via DPP tree (R8-validated) ----
#pragma unroll
                for (int q = 0; q < 10; ++q) {
                    float v  = f[q];
                    float t1 = v  + dppshl<0x101>(v);
                    float t2 = t1 + dppshl<0x102>(t1);
                    float t3 = t2 + dppshl<0x104>(t1);
                    float g  = t3 + dppshl<0x106>(v);
                    run[q] += g - ring[slot][q];
                    ring[slot][q] = g;
                }

                // ---- SSIM for 2 outputs ----
                if (s >= 6) {
#pragma unroll
                    for (int j = 0; j < 2; ++j) {
                        const bool vld = j ? vld1 : vld0;
                        if (vld) {
                            float Sx  = run[0 + j];
                            float Sy  = run[2 + j];
                            float Sxx = run[4 + j];
                            float Syy = run[6 + j];
                            float Sxy = run[8 + j];
                            float P = Sx * Sy;
                            float Q = fmaf(Sx, Sx, Sy * Sy);
                            float A1 = fmaf(2.f, P, c1s);
                            float A2 = fmaf(kkA, fmaf(-tni, P, Sxy), c2s);
                            float B1 = Q + c1s;
                            float B2 = fmaf(kkB, fmaf(-tni, Q, Sxx + Syy), c2s);
                            float num = A1 * A2;
                            float den = B1 * B2;
                            float r0 = __builtin_amdgcn_rcpf(den);
                            r0 = r0 * fmaf(-den, r0, 2.0f);   // 1 Newton step
                            acc = fmaf(num, r0, acc);
                        }
                    }
                }
            }
        }
    }

    // ---- reduction: wave shuffle -> LDS -> per-block partial (double) ----
#pragma unroll
    for (int off = 32; off; off >>= 1) acc += __shfl_down(acc, off);
    if (lane == 0) sm[wave] = acc;
    __syncthreads();
    if (tid == 0) {
        double t = (double)sm[0] + (double)sm[1] + (double)sm[2] + (double)sm[3];
        if (mode) wsout[blockIdx.x] = t;
        else      atomicAdd(wsout, t);
    }
}

__global__ void ssim3d_finalize(const double* __restrict__ ws, float* __restrict__ out, int mode)
{
    if (mode) {
        __shared__ double sm[4];
        const int tid = threadIdx.x;
        double t = 0.0;
        for (int i = tid; i < NBLK; i += 256) t += ws[i];
#pragma unroll
        for (int off = 32; off; off >>= 1) t += __shfl_down(t, off);
        if ((tid & 63) == 0) sm[tid >> 6] = t;
        __syncthreads();
        if (tid == 0) {
            double r = sm[0] + sm[1] + sm[2] + sm[3];
            out[0] = (float)(r * (1.0 / 7263392.0));   // 4 * 122^3
        }
    } else {
        if (threadIdx.x == 0)
            out[0] = (float)(ws[0] * (1.0 / 7263392.0));
    }
}

extern "C" void kernel_launch(void* const* d_in, const int* in_sizes, int n_in,
                              void* d_out, int out_size, void* d_ws, size_t ws_size,
                              hipStream_t stream)
{
    const float* X  = (const float*)d_in[0];
    const float* Y  = (const float*)d_in[1];
    const float* DR = (const float*)d_in[2];
    double* ws = (double*)d_ws;

    const int mode = (ws_size >= NBLK * sizeof(double)) ? 1 : 0;
    if (!mode) hipMemsetAsync(d_ws, 0, sizeof(double), stream);
    ssim3d_kernel<<<NBLK, 256, 0, stream>>>(X, Y, DR, ws, mode);
    ssim3d_finalize<<<1, 256, 0, stream>>>(ws, (float*)d_out, mode);
}